// Round 1
// baseline (1793.129 us; speedup 1.0000x reference)
//
#include <hip/hip_runtime.h>

#define D      1024
#define DR     256
#define NSTAGE 4
#define G      8
#define NG     128
#define P      40
#define RPB    2      // rows per block; block = RPB*NG/… = 256 threads, 1 (row,group) pair per thread

__global__ __launch_bounds__(256, 2) void ldrfm_kernel(
    const float* __restrict__ x,   // [N, D]
    const float* __restrict__ Wi,  // [B, DR, 2P]
    const float* __restrict__ bi,  // [B, DR]
    const float* __restrict__ Wo,  // [B, G, DR]
    float* __restrict__ out,       // [N, D]
    int nrows)
{
    __shared__ __align__(16) float xs[RPB][D];
    __shared__ __align__(16) float zs[RPB][D];

    const int tid   = threadIdx.x;
    const int row_l = tid >> 7;      // 0..RPB-1
    const int g     = tid & (NG - 1);
    const int row0  = blockIdx.x * RPB;

    // ---- cooperative load: RPB rows x D floats, float4-coalesced; z starts as x
    {
        const float4* xg4 = reinterpret_cast<const float4*>(x + (size_t)row0 * D);
        float4* xs4 = reinterpret_cast<float4*>(&xs[0][0]);
        float4* zs4 = reinterpret_cast<float4*>(&zs[0][0]);
#pragma unroll
        for (int k = 0; k < (RPB * D / 4) / 256; ++k) {
            float4 v = xg4[tid + k * 256];
            xs4[tid + k * 256] = v;
            zs4[tid + k * 256] = v;
        }
    }
    __syncthreads();

    // window start: multiple of 8 -> all float4 sub-reads stay 16B aligned even across wrap
    const int s0 = (g * G - 2 * G) & (D - 1);

    float y[2 * P];

    for (int st = 0; st < NSTAGE; ++st) {
        // ---- gather window into registers (compile-time indices only)
#pragma unroll
        for (int p = 0; p < P; p += 4) {
            int idx = (s0 + p) & (D - 1);
            float4 v = *reinterpret_cast<const float4*>(&xs[row_l][idx]);
            y[p] = v.x; y[p + 1] = v.y; y[p + 2] = v.z; y[p + 3] = v.w;
        }
#pragma unroll
        for (int p = 0; p < P; p += 4) {
            int idx = (s0 + p) & (D - 1);
            float4 v = *reinterpret_cast<const float4*>(&zs[row_l][idx]);
            y[P + p] = v.x; y[P + p + 1] = v.y; y[P + p + 2] = v.z; y[P + p + 3] = v.w;
        }
        __syncthreads();   // all window reads done before anyone overwrites zs

        const float* Wi_s = Wi + (size_t)st * DR * 2 * P;
        const float* bi_s = bi + (size_t)st * DR;
        const float* Wo_s = Wo + (size_t)st * G * DR;

        float acc[G];
#pragma unroll
        for (int c = 0; c < G; ++c) acc[c] = 0.f;

        for (int r = 0; r < DR; ++r) {
            const float* w = Wi_s + r * (2 * P);   // wave-uniform -> scalar loads
            float p0 = bi_s[r], p1 = 0.f, p2 = 0.f, p3 = 0.f;
#pragma unroll
            for (int p = 0; p < 2 * P; p += 4) {
                p0 = fmaf(w[p],     y[p],     p0);
                p1 = fmaf(w[p + 1], y[p + 1], p1);
                p2 = fmaf(w[p + 2], y[p + 2], p2);
                p3 = fmaf(w[p + 3], y[p + 3], p3);
            }
            float v = (p0 + p1) + (p2 + p3);
            // tanh(v) = sign(v) * (1-e)/(1+e), e = exp(-2|v|) in (0,1] -> no overflow
            float e  = __expf(-2.f * fabsf(v));
            float t  = (1.f - e) * __builtin_amdgcn_rcpf(1.f + e);
            float th = copysignf(t, v);
#pragma unroll
            for (int c = 0; c < G; ++c)
                acc[c] = fmaf(Wo_s[c * DR + r], th, acc[c]);
        }

        if (st < NSTAGE - 1) {
#pragma unroll
            for (int c = 0; c < G; ++c) zs[row_l][g * G + c] = acc[c];
            __syncthreads();
        } else {
            float4* o4 = reinterpret_cast<float4*>(out + (size_t)(row0 + row_l) * D + g * G);
            float4 a, b;
            a.x = acc[0]; a.y = acc[1]; a.z = acc[2]; a.w = acc[3];
            b.x = acc[4]; b.y = acc[5]; b.z = acc[6]; b.w = acc[7];
            o4[0] = a; o4[1] = b;
        }
    }
}

extern "C" void kernel_launch(void* const* d_in, const int* in_sizes, int n_in,
                              void* d_out, int out_size, void* d_ws, size_t ws_size,
                              hipStream_t stream) {
    const float* x  = (const float*)d_in[0];
    const float* Wi = (const float*)d_in[1];
    const float* bi = (const float*)d_in[2];
    const float* Wo = (const float*)d_in[3];
    float* out = (float*)d_out;

    int nrows = in_sizes[0] / D;            // 4096
    dim3 grid(nrows / RPB);                 // 2048 blocks
    ldrfm_kernel<<<grid, 256, 0, stream>>>(x, Wi, bi, Wo, out, nrows);
}

// Round 2
// 497.446 us; speedup vs baseline: 3.6047x; 3.6047x over previous
//
#include <hip/hip_runtime.h>

#define D_   1024
#define DR_  256
#define NST_ 4
#define PW   80     // 2P

typedef _Float16 h4 __attribute__((ext_vector_type(4)));
typedef _Float16 h8 __attribute__((ext_vector_type(8)));
typedef float    f4 __attribute__((ext_vector_type(4)));

#define MFMA32(A, B, C) __builtin_amdgcn_mfma_f32_16x16x32_f16(A, B, C, 0, 0, 0)

__device__ __forceinline__ float fast_tanh(float v) {
    float a = fminf(2.f * v, 80.f);               // overflow guard; exp(-big)->0 is fine
    float e = __expf(a);
    return (e - 1.f) * __builtin_amdgcn_rcpf(e + 1.f);
}

__device__ __forceinline__ h8 ldcvt8(const float* __restrict__ p) {
    f4 a = *(const f4*)p;
    f4 b = *(const f4*)(p + 4);
    h8 r;
    r[0] = (_Float16)a[0]; r[1] = (_Float16)a[1]; r[2] = (_Float16)a[2]; r[3] = (_Float16)a[3];
    r[4] = (_Float16)b[0]; r[5] = (_Float16)b[1]; r[6] = (_Float16)b[2]; r[7] = (_Float16)b[3];
    return r;
}

__global__ __launch_bounds__(256, 2) void ldrfm_mfma(
    const float* __restrict__ x,    // [N, 1024]
    const float* __restrict__ Wi,   // [4, 256, 80]
    const float* __restrict__ bi,   // [4, 256]
    const float* __restrict__ Wo,   // [4, 8, 256]
    float* __restrict__ out)        // [N, 1024]
{
    // Y chunk-major: [k-chunk 0..11][pair 0..255][8 f16]; chunks 0-4 = x-window,
    // 5-9 = z-window, 10-11 = zero pad (K 80->96). One B-frag = one ds_read_b128.
    __shared__ __align__(16) _Float16 Ys[12][256][8];
    __shared__ __align__(16) _Float16 Hs[4][8][16][8];   // per-wave H tile, B2-frag layout
    __shared__ __align__(16) _Float16 xh[2 * D_];
    __shared__ __align__(16) _Float16 zh[2 * D_];
    __shared__ __align__(16) float    zf[256 * 8];       // GEMM2 accumulator (f32)

    const int tid  = threadIdx.x;
    const int w    = tid >> 6;
    const int lane = tid & 63;
    const int p16  = lane & 15;
    const int q    = lane >> 4;
    const int row0 = blockIdx.x * 2;

    // ---- init: x rows -> fp16 xh & zh; zero zf and Y pad chunks
    {
        const f4* xr = (const f4*)(x + (size_t)row0 * D_);
        f4 v0 = xr[2 * tid], v1 = xr[2 * tid + 1];
        h8 hv;
        hv[0] = (_Float16)v0[0]; hv[1] = (_Float16)v0[1]; hv[2] = (_Float16)v0[2]; hv[3] = (_Float16)v0[3];
        hv[4] = (_Float16)v1[0]; hv[5] = (_Float16)v1[1]; hv[6] = (_Float16)v1[2]; hv[7] = (_Float16)v1[3];
        ((h8*)xh)[tid] = hv;
        ((h8*)zh)[tid] = hv;
        f4 z4 = {0.f, 0.f, 0.f, 0.f};
        ((f4*)zf)[2 * tid]     = z4;
        ((f4*)zf)[2 * tid + 1] = z4;
        h8 hz = {0, 0, 0, 0, 0, 0, 0, 0};
        *(h8*)&Ys[10][tid][0] = hz;
        *(h8*)&Ys[11][tid][0] = hz;
    }
    __syncthreads();

    // ---- build Y: both halves from x initially (z starts equal to x)
    {
        const int nl = tid >> 7, g = tid & 127;
        const int s0 = (g * 8 - 16) & (D_ - 1);   // window start, multiple of 8
#pragma unroll
        for (int j = 0; j < 5; ++j) {
            int idx = (s0 + 8 * j) & (D_ - 1);
            h8 c = *(const h8*)&xh[nl * D_ + idx];
            *(h8*)&Ys[j][tid][0]     = c;
            *(h8*)&Ys[5 + j][tid][0] = c;
        }
    }
    __syncthreads();

#pragma unroll 1
    for (int st = 0; st < NST_; ++st) {
        const float* Wis = Wi + st * (DR_ * PW);
        const float* bis = bi + st * DR_;
        const float* Wos = Wo + st * (8 * DR_);

        // ---- per-stage register fragments (wave owns r in [64w, 64w+64))
        h8 wA0[4], wA1[4], wA2[4];
        f4 biv[4];
#pragma unroll
        for (int rt = 0; rt < 4; ++rt) {
            const int r = (4 * w + rt) * 16 + p16;
            const float* wr = Wis + r * PW;
            wA0[rt] = ldcvt8(wr + q * 8);
            wA1[rt] = ldcvt8(wr + 32 + q * 8);
            // K tail: k = 64 + q*8 + j valid only for q<2; keep addresses in-bounds
            h8 t = ldcvt8(wr + 64 + (q & 1) * 8);
            h8 hz = {0, 0, 0, 0, 0, 0, 0, 0};
            wA2[rt] = (q < 2) ? t : hz;
            biv[rt] = *(const f4*)(bis + (4 * w + rt) * 16 + q * 4);
        }
        const int cw = p16 & 7;   // Wo rows padded 8->16: rows 8..15 garbage, discarded
        const h8 wB0 = ldcvt8(Wos + cw * DR_ + 64 * w + q * 8);
        const h8 wB1 = ldcvt8(Wos + cw * DR_ + 64 * w + 32 + q * 8);

#pragma unroll 2
        for (int pt = 0; pt < 16; ++pt) {
            const int pcol = pt * 16 + p16;
            const h8 b0 = *(const h8*)&Ys[q][pcol][0];
            const h8 b1 = *(const h8*)&Ys[4 + q][pcol][0];
            const h8 b2 = *(const h8*)&Ys[8 + q][pcol][0];

            f4 acc[4];
#pragma unroll
            for (int rt = 0; rt < 4; ++rt) acc[rt] = biv[rt];     // bias pre-load
#pragma unroll
            for (int rt = 0; rt < 4; ++rt) acc[rt] = MFMA32(wA0[rt], b0, acc[rt]);
#pragma unroll
            for (int rt = 0; rt < 4; ++rt) acc[rt] = MFMA32(wA1[rt], b1, acc[rt]);
#pragma unroll
            for (int rt = 0; rt < 4; ++rt) acc[rt] = MFMA32(wA2[rt], b2, acc[rt]);

            // tanh -> f16 -> wave-private H tile (B2-frag layout: [chunk][pair16][8])
#pragma unroll
            for (int rt = 0; rt < 4; ++rt) {
                float t0 = fast_tanh(acc[rt][0]);
                float t1 = fast_tanh(acc[rt][1]);
                float t2 = fast_tanh(acc[rt][2]);
                float t3 = fast_tanh(acc[rt][3]);
                h4 hv;
                hv[0] = (_Float16)t0; hv[1] = (_Float16)t1;
                hv[2] = (_Float16)t2; hv[3] = (_Float16)t3;
                *(h4*)&Hs[w][rt * 2 + (q >> 1)][p16][(q & 1) * 4] = hv;
            }

            // GEMM2: split-K by wave (K=64 each), atomically reduce into zf
            const h8 hb0 = *(const h8*)&Hs[w][q][p16][0];
            const h8 hb1 = *(const h8*)&Hs[w][4 + q][p16][0];
            f4 c2 = {0.f, 0.f, 0.f, 0.f};
            c2 = MFMA32(wB0, hb0, c2);
            c2 = MFMA32(wB1, hb1, c2);
            if (q < 2) {                       // rows c = q*4+reg in 0..7 are real
                float* zp = &zf[pcol * 8 + q * 4];
                atomicAdd(zp + 0, c2[0]);
                atomicAdd(zp + 1, c2[1]);
                atomicAdd(zp + 2, c2[2]);
                atomicAdd(zp + 3, c2[3]);
            }
        }

        __syncthreads();   // all waves' zf atomics done
        {
            f4 za = *(const f4*)&zf[8 * tid];
            f4 zb = *(const f4*)&zf[8 * tid + 4];
            if (st < NST_ - 1) {
                f4 z4 = {0.f, 0.f, 0.f, 0.f};
                *(f4*)&zf[8 * tid]     = z4;   // re-zero own slots for next stage
                *(f4*)&zf[8 * tid + 4] = z4;
                h8 hv;
                hv[0] = (_Float16)za[0]; hv[1] = (_Float16)za[1];
                hv[2] = (_Float16)za[2]; hv[3] = (_Float16)za[3];
                hv[4] = (_Float16)zb[0]; hv[5] = (_Float16)zb[1];
                hv[6] = (_Float16)zb[2]; hv[7] = (_Float16)zb[3];
                ((h8*)zh)[tid] = hv;           // pair tid -> z[nl][g*8..g*8+8)
            } else {
                f4* op = (f4*)(out + (size_t)row0 * D_);
                op[2 * tid]     = za;          // final z written in f32 (no f16 round)
                op[2 * tid + 1] = zb;
            }
        }
        if (st < NST_ - 1) {
            __syncthreads();   // zh ready, zf zeroed
            const int nl = tid >> 7, g = tid & 127;
            const int s0 = (g * 8 - 16) & (D_ - 1);
#pragma unroll
            for (int j = 0; j < 5; ++j) {
                int idx = (s0 + 8 * j) & (D_ - 1);
                *(h8*)&Ys[5 + j][tid][0] = *(const h8*)&zh[nl * D_ + idx];
            }
            __syncthreads();   // Y z-half rebuilt before next stage's GEMM1
        }
    }
}

extern "C" void kernel_launch(void* const* d_in, const int* in_sizes, int n_in,
                              void* d_out, int out_size, void* d_ws, size_t ws_size,
                              hipStream_t stream) {
    const float* x  = (const float*)d_in[0];
    const float* Wi = (const float*)d_in[1];
    const float* bi = (const float*)d_in[2];
    const float* Wo = (const float*)d_in[3];
    float* out = (float*)d_out;

    int nrows = in_sizes[0] / D_;          // 4096
    dim3 grid(nrows / 2);                  // 2048 blocks, 2 rows each
    ldrfm_mfma<<<grid, 256, 0, stream>>>(x, Wi, bi, Wo, out);
}

// Round 3
// 297.276 us; speedup vs baseline: 6.0319x; 1.6733x over previous
//
#include <hip/hip_runtime.h>

#define D_ 1024

typedef _Float16 h4 __attribute__((ext_vector_type(4)));
typedef _Float16 h8 __attribute__((ext_vector_type(8)));
typedef float    f4 __attribute__((ext_vector_type(4)));

#define MFMA(A, B, C) __builtin_amdgcn_mfma_f32_16x16x32_f16(A, B, C, 0, 0, 0)

__device__ __forceinline__ float fast_tanh(float v) {
    float a = fminf(v + v, 80.f);                 // exp(-big)->0 handles v<<0
    float e = __expf(a);
    return fmaf(-2.f, __builtin_amdgcn_rcpf(e + 1.f), 1.f);
}

// ---- pre-pass 1: Wi f32[4][256][80] + bi[4][256] -> Wi16 h8[st][rt 16][chunk 12][p16 16]
// chunk 0-9 = real K (k = chunk*8+j); chunk 10 = [bias,0x7] (bias folded via B=e0); chunk 11 = 0
__global__ void prep_wi(const float* __restrict__ Wi, const float* __restrict__ bi,
                        h8* __restrict__ Wi16) {
    int t = blockIdx.x * 256 + threadIdx.x;
    if (t >= 4 * 16 * 12 * 16) return;
    int p16 = t & 15;
    int chunk = (t >> 4) % 12;
    int rt = ((t >> 4) / 12) & 15;
    int st = t / 3072;
    int r = rt * 16 + p16;
    h8 v = {0, 0, 0, 0, 0, 0, 0, 0};
    if (chunk < 10) {
        const float* s = Wi + ((size_t)(st * 256 + r) * 80 + chunk * 8);
#pragma unroll
        for (int j = 0; j < 8; ++j) v[j] = (_Float16)s[j];
    } else if (chunk == 10) {
        v[0] = (_Float16)bi[st * 256 + r];
    }
    Wi16[t] = v;
}

// ---- pre-pass 2: Wo f32[4][8][256] -> Wo16 h8[st][kc 8][q 4][p16 16]; rows c>=8 zero-padded
__global__ void prep_wo(const float* __restrict__ Wo, h8* __restrict__ Wo16) {
    int t = blockIdx.x * 256 + threadIdx.x;
    if (t >= 4 * 8 * 4 * 16) return;
    int p16 = t & 15;
    int q = (t >> 4) & 3;
    int kc = (t >> 6) & 7;
    int st = t >> 9;
    h8 v = {0, 0, 0, 0, 0, 0, 0, 0};
    if (p16 < 8) {
        const float* s = Wo + ((size_t)(st * 8 + p16) * 256 + kc * 32 + q * 8);
#pragma unroll
        for (int j = 0; j < 8; ++j) v[j] = (_Float16)s[j];
    }
    Wo16[t] = v;
}

// ---- main: 1 wave = 1 row, barrier-free; 4 waves/block
__global__ __launch_bounds__(256, 2) void ldrfm3(
    const float* __restrict__ x,     // [N,1024]
    const h8* __restrict__ Wi16,     // [4][16][12][16]
    const h8* __restrict__ Wo16,     // [4][8][4][16]
    float* __restrict__ out)         // [N,1024]
{
    __shared__ h8 xh8[4][128];       // per-row x (f16), 2 KB each
    __shared__ h8 zb[2][4][128];     // per-row z double-buffer
    __shared__ h8 hbuf[4][4][16];    // per-wave H exchange tile (1 KB), wave-synchronous

    const int tid = threadIdx.x;
    const int w = tid >> 6, lane = tid & 63;
    const int p16 = lane & 15, q = lane >> 4;
    const int row = blockIdx.x * 4 + w;

    // load + convert own row: 16 f32/lane -> 2 h8 slots
    {
        const f4* xr = (const f4*)(x + (size_t)row * D_) + lane * 4;
        f4 v0 = xr[0], v1 = xr[1], v2 = xr[2], v3 = xr[3];
        h8 h0, h1;
        h0[0] = (_Float16)v0[0]; h0[1] = (_Float16)v0[1]; h0[2] = (_Float16)v0[2]; h0[3] = (_Float16)v0[3];
        h0[4] = (_Float16)v1[0]; h0[5] = (_Float16)v1[1]; h0[6] = (_Float16)v1[2]; h0[7] = (_Float16)v1[3];
        h1[0] = (_Float16)v2[0]; h1[1] = (_Float16)v2[1]; h1[2] = (_Float16)v2[2]; h1[3] = (_Float16)v2[3];
        h1[4] = (_Float16)v3[0]; h1[5] = (_Float16)v3[1]; h1[6] = (_Float16)v3[2]; h1[7] = (_Float16)v3[3];
        xh8[w][2 * lane] = h0; xh8[w][2 * lane + 1] = h1;
        zb[0][w][2 * lane] = h0; zb[0][w][2 * lane + 1] = h1;
    }

    const h8 HZ = {0, 0, 0, 0, 0, 0, 0, 0};
    h8 HE0 = HZ; HE0[0] = (_Float16)1.0f;

    // wave-private H exchange addresses (constant over all loops)
    _Float16* hb = (_Float16*)&hbuf[w][0][0];
    h4* hw0 = (h4*)(hb + (((q >> 1) * 16 + p16) * 8 + (q & 1) * 4));        // rt even
    h4* hw1 = (h4*)(hb + ((((q >> 1) + 2) * 16 + p16) * 8 + (q & 1) * 4));  // rt odd
    const h8* hr = (const h8*)(hb + (q * 16 + p16) * 8);

#pragma unroll 1
    for (int st = 0; st < 4; ++st) {
        const h8* WiS = Wi16 + st * 3072;
        const h8* WoS = Wo16 + st * 512;
        h8* zcur = &zb[st & 1][w][0];
        h8* znxt = &zb[(st + 1) & 1][w][0];

        // A-fragments for the whole stage: 48 coalesced 1KB bursts -> 192 VGPR
        h8 wA[16][3];
#pragma unroll
        for (int rt = 0; rt < 16; ++rt)
#pragma unroll
            for (int cg = 0; cg < 3; ++cg)
                wA[rt][cg] = WiS[(rt * 12 + cg * 4 + q) * 16 + p16];

#pragma unroll 1
        for (int pt = 0; pt < 8; ++pt) {
            const int pair = pt * 16 + p16;
            // window B-fragments: contiguous h8 slices of x/z row buffers
            h8 b0 = xh8[w][(pair + q - 2) & 127];
            const h8* s1 = (q == 0) ? &xh8[w][0] : zcur;
            int i1 = (q == 0) ? ((pair + 2) & 127) : ((pair + q - 3) & 127);
            h8 b1 = s1[i1];
            h8 b2 = zcur[(pair + 1 + (q & 1)) & 127];
            if (q == 2) b2 = HE0;   // bias column selector (A chunk 10 holds bias)
            if (q == 3) b2 = HZ;    // K-pad

            f4 acc2 = {0.f, 0.f, 0.f, 0.f};
#pragma unroll
            for (int kc = 0; kc < 8; ++kc) {
                h8 wB = WoS[(kc * 4 + q) * 16 + p16];
                f4 z4 = {0.f, 0.f, 0.f, 0.f};
                f4 a0 = MFMA(wA[2 * kc][2], b2, z4);
                a0    = MFMA(wA[2 * kc][1], b1, a0);
                a0    = MFMA(wA[2 * kc][0], b0, a0);
                f4 a1 = MFMA(wA[2 * kc + 1][2], b2, z4);
                a1    = MFMA(wA[2 * kc + 1][1], b1, a1);
                a1    = MFMA(wA[2 * kc + 1][0], b0, a1);

                h4 h0, h1;
                h0[0] = (_Float16)fast_tanh(a0[0]);
                h0[1] = (_Float16)fast_tanh(a0[1]);
                h0[2] = (_Float16)fast_tanh(a0[2]);
                h0[3] = (_Float16)fast_tanh(a0[3]);
                h1[0] = (_Float16)fast_tanh(a1[0]);
                h1[1] = (_Float16)fast_tanh(a1[1]);
                h1[2] = (_Float16)fast_tanh(a1[2]);
                h1[3] = (_Float16)fast_tanh(a1[3]);
                *hw0 = h0;                 // wave-synchronous LDS transpose
                *hw1 = h1;                 // (C-layout -> B-layout), no barrier
                h8 hbv = *hr;
                acc2 = MFMA(wB, hbv, acc2);
            }

            if (st < 3) {
                if (q < 2) {               // lanes q<2 hold the 8 real output rows
                    h4 zv;
                    zv[0] = (_Float16)acc2[0]; zv[1] = (_Float16)acc2[1];
                    zv[2] = (_Float16)acc2[2]; zv[3] = (_Float16)acc2[3];
                    *(h4*)((_Float16*)&znxt[pair] + q * 4) = zv;
                }
            } else {
                if (q < 2) {
                    *(f4*)(out + (size_t)row * D_ + pair * 8 + q * 4) = acc2;
                }
            }
        }
    }
}

extern "C" void kernel_launch(void* const* d_in, const int* in_sizes, int n_in,
                              void* d_out, int out_size, void* d_ws, size_t ws_size,
                              hipStream_t stream) {
    const float* x  = (const float*)d_in[0];
    const float* Wi = (const float*)d_in[1];
    const float* bi = (const float*)d_in[2];
    const float* Wo = (const float*)d_in[3];
    float* out = (float*)d_out;

    h8* Wi16 = (h8*)d_ws;                   // 12288 h8 = 192 KB
    h8* Wo16 = Wi16 + 12288;                // 2048 h8 = 32 KB

    prep_wi<<<48, 256, 0, stream>>>(Wi, bi, Wi16);
    prep_wo<<<8, 256, 0, stream>>>(Wo, Wo16);

    int nrows = in_sizes[0] / D_;           // 4096
    ldrfm3<<<nrows / 4, 256, 0, stream>>>(x, Wi16, Wo16, out);
}